// Round 7
// baseline (113.301 us; speedup 1.0000x reference)
//
#include <hip/hip_runtime.h>
#include <math.h>

#define BB 8
#define HH 256
#define WW 256
#define NPIX (BB*HH*WW)
#define NROWS (BB*HH)   // 2048

// ws layout (byte offsets):
//   [0]      float    part_max[2048]      per-row max dist
//   [8192]   double   part_sum[2048]      per-row sum(phi*prob)
//   [24576]  int      part_fg[2048]       per-row has-fg flag
//   [32768]  unsigned fg_words[8][8][256] column fg bitmasks (64 KB):
//                                         word w of col j, bit r = row 32*w+r
//   [98304]  unsigned cnt[9]              bcnt[8] + gcnt  (zeroed by maskbuild)
//   [98368]  double   terms[8]            per-batch sum/denom  (written before read)

// k1: build column bitmasks, coalesced. Block = (batch, 32-row band).
// Block 0 also zeroes the reduction counters (runs before k2 in stream order).
__global__ void maskbuild(const int* __restrict__ tgt,
                          unsigned* __restrict__ fg_words,
                          unsigned* __restrict__ cnt) {
    if (blockIdx.x == 0 && threadIdx.x < 9) cnt[threadIdx.x] = 0u;
    int blk = blockIdx.x;            // b*8 + band
    int b = blk >> 3, band = blk & 7;
    int j = threadIdx.x;
    const int* base = tgt + b * (HH * WW) + (band * 32) * WW + j;
    unsigned bits = 0;
    #pragma unroll
    for (int r = 0; r < 32; ++r)
        bits |= (base[r * WW] != 0 ? 1u : 0u) << r;
    fg_words[b * 2048 + band * 256 + j] = bits;
}

// k2: one block per (b,i) row — R6's proven core, mask words global->reg
// (maskL LDS removed: thread j only ever read its own column's words).
// Fused hierarchical reduce: last block per batch folds the batch, last
// batch-finisher writes the scalar (device-scope atomics + threadfence).
__global__ void edt_row(const unsigned* __restrict__ fg_words,
                        const float* __restrict__ pred,
                        float* __restrict__ part_max,
                        double* __restrict__ part_sum,
                        int* __restrict__ part_fg,
                        unsigned* __restrict__ cnt,
                        double* __restrict__ terms,
                        float* __restrict__ out) {
    __shared__ float sB[3 * WW];          // dist_to_bg^2 at WW+jp, 1e30 pads
    __shared__ float sF[3 * WW];          // dist_to_fg^2
    __shared__ float wmax[4];
    __shared__ double wsum[4];
    __shared__ int wfg[4];
    __shared__ int amLast, amLastG;

    int row = blockIdx.x;                 // b*HH + i
    int b = row >> 8, i = row & 255;
    int j = threadIdx.x;

    float x = pred[row * WW + j];         // independent, issue early

    // own-column mask words, coalesced across j for each w
    const unsigned* mb = fg_words + b * 2048;
    unsigned mw[8];
    #pragma unroll
    for (int w = 0; w < 8; ++w) mw[w] = mb[w * 256 + j];

    // vertical distances for (i, col j) from the 256-bit column mask
    const int BIGI = 1 << 20;
    int pF = -BIGI, pB = -BIGI, nF = BIGI, nB = BIGI;
    #pragma unroll
    for (int w = 0; w < 4; ++w) {
        unsigned long long v = (unsigned long long)mw[2 * w]
                             | ((unsigned long long)mw[2 * w + 1] << 32);
        unsigned long long g = ~v;
        int d = i - 64 * w;               // my bit position within this word
        unsigned long long bf = (d >= 63) ? v : ((d < 0) ? 0ull : (v & (~0ull >> (63 - d))));
        unsigned long long bb = (d >= 63) ? g : ((d < 0) ? 0ull : (g & (~0ull >> (63 - d))));
        if (bf) pF = 64 * w + 63 - __builtin_clzll(bf);   // w ascending => max
        if (bb) pB = 64 * w + 63 - __builtin_clzll(bb);
        unsigned long long af = (d <= 0) ? v : ((d > 63) ? 0ull : (v & (~0ull << d)));
        unsigned long long ab = (d <= 0) ? g : ((d > 63) ? 0ull : (g & (~0ull << d)));
        if (af) nF = min(nF, 64 * w + __builtin_ctzll(af));
        if (ab) nB = min(nB, 64 * w + __builtin_ctzll(ab));
    }
    int gF = min(min(i - pF, nF - i), 512);   // dist to nearest fg (0 if own fg)
    int gB = min(min(i - pB, nB - i), 512);   // dist to nearest bg
    bool isFg = (gF == 0);
    unsigned long long fgb = __ballot(isFg);

    float fF = (float)gF, fB = (float)gB;
    sF[j] = 1e30f; sF[2 * WW + j] = 1e30f; sF[WW + j] = fF * fF;
    sB[j] = 1e30f; sB[2 * WW + j] = 1e30f; sB[WW + j] = fB * fB;
    __syncthreads();

    // pruned exact 1D EDT over the OPPOSITE class (own-class dist is 0)
    const float* sp = isFg ? sB : sF;
    float m = isFg ? fB * fB : fF * fF;
    int idx = WW + j;
    for (int k = 1; k < WW; ++k) {
        float k2 = (float)(k * k);
        if (k2 >= m) break;               // exact termination (monotone offsets)
        m = fminf(m, sp[idx - k] + k2);
        m = fminf(m, sp[idx + k] + k2);
    }
    float dist = sqrtf(m);
    float phi = isFg ? -dist : dist;
    float prob = 1.0f / (1.0f + expf(-x));
    double sd = (double)(phi * prob);
    float mx = dist;

    #pragma unroll
    for (int off = 32; off; off >>= 1) {
        mx = fmaxf(mx, __shfl_down(mx, off));
        sd += __shfl_down(sd, off);
    }
    int wid = j >> 6;
    if ((j & 63) == 0) { wmax[wid] = mx; wsum[wid] = sd; wfg[wid] = (fgb != 0ull); }
    __syncthreads();
    if (j == 0) {
        part_max[row] = fmaxf(fmaxf(wmax[0], wmax[1]), fmaxf(wmax[2], wmax[3]));
        part_sum[row] = wsum[0] + wsum[1] + wsum[2] + wsum[3];
        part_fg[row] = wfg[0] | wfg[1] | wfg[2] | wfg[3];
        __threadfence();                               // release partials
        unsigned old = atomicAdd(&cnt[b], 1u);
        amLast = (old == (unsigned)(HH - 1));
    }
    __syncthreads();
    if (!amLast) return;

    // ---- last block of batch b: fold the 256 row partials (coalesced)
    __threadfence();                                   // acquire partials
    int base = b * HH;
    float mx2 = part_max[base + j];
    double sd2 = part_sum[base + j];
    int fg2 = part_fg[base + j];
    #pragma unroll
    for (int off = 32; off; off >>= 1) {
        mx2 = fmaxf(mx2, __shfl_down(mx2, off));
        sd2 += __shfl_down(sd2, off);
        fg2 |= __shfl_down(fg2, off);
    }
    if ((j & 63) == 0) { wmax[wid] = mx2; wsum[wid] = sd2; wfg[wid] = fg2; }
    __syncthreads();
    if (j == 0) {
        float M = fmaxf(fmaxf(wmax[0], wmax[1]), fmaxf(wmax[2], wmax[3]));
        double S = wsum[0] + wsum[1] + wsum[2] + wsum[3];
        int F = wfg[0] | wfg[1] | wfg[2] | wfg[3];
        terms[b] = F ? S / ((double)M + 1e-8) : 0.0;
        __threadfence();                               // release term
        unsigned o2 = atomicAdd(&cnt[8], 1u);
        amLastG = (o2 == (unsigned)(BB - 1));
    }
    __syncthreads();
    if (amLastG && j == 0) {
        __threadfence();                               // acquire terms
        double tot = 0.0;
        #pragma unroll
        for (int q = 0; q < BB; ++q) tot += terms[q];
        out[0] = (float)(tot / (double)NPIX);
    }
}

extern "C" void kernel_launch(void* const* d_in, const int* in_sizes, int n_in,
                              void* d_out, int out_size, void* d_ws, size_t ws_size,
                              hipStream_t stream) {
    const float* pred = (const float*)d_in[0];
    const int* tgt = (const int*)d_in[1];
    float* out = (float*)d_out;

    char* ws = (char*)d_ws;
    float* part_max = (float*)ws;                  // 2048 floats
    double* part_sum = (double*)(ws + 8192);       // 2048 doubles
    int* part_fg = (int*)(ws + 24576);             // 2048 ints
    unsigned* fg_words = (unsigned*)(ws + 32768);  // 16384 u32 (64 KB)
    unsigned* cnt = (unsigned*)(ws + 98304);       // bcnt[8] + gcnt
    double* terms = (double*)(ws + 98368);         // 8 doubles

    maskbuild<<<64, 256, 0, stream>>>(tgt, fg_words, cnt);
    edt_row<<<NROWS, WW, 0, stream>>>(fg_words, pred, part_max, part_sum,
                                      part_fg, cnt, terms, out);
}